// Round 6
// baseline (608.206 us; speedup 1.0000x reference)
//
#include <hip/hip_runtime.h>

typedef unsigned short u16;
typedef __bf16 bf16x8 __attribute__((ext_vector_type(8)));
typedef float   f32x4 __attribute__((ext_vector_type(4)));
typedef unsigned short u16x8 __attribute__((ext_vector_type(8)));

// ---------- helpers ----------
__device__ __forceinline__ u16 f2bf(float f) {
    unsigned int u = __builtin_bit_cast(unsigned int, f);
    u = u + 0x7FFFu + ((u >> 16) & 1u);   // round-to-nearest-even
    return (u16)(u >> 16);
}
__device__ __forceinline__ void gload16(const void* g, void* l) {
    __builtin_amdgcn_global_load_lds(
        (__attribute__((address_space(1))) void*)g,
        (__attribute__((address_space(3))) void*)l,
        16, 0, 0);
}

#define S_BARRIER() asm volatile("s_barrier" ::: "memory")

// ---------- device-scope flag protocol (guide §6 G16 pattern) ----------
// producer: __syncthreads() (per-thread vmcnt(0) drain) -> tid0 threadfence
// (agent release / L2 writeback) + release-add.
// consumer: tid0 acquire-load spin (invalidates CU L1 + XCD L2; covers all
// waves of the block — same CU) -> __syncthreads().
__device__ __forceinline__ void task_done(int tid, int* f) {
    __syncthreads();
    if (tid == 0) {
        __threadfence();
        __hip_atomic_fetch_add(f, 1, __ATOMIC_RELEASE, __HIP_MEMORY_SCOPE_AGENT);
    }
}
__device__ __forceinline__ void wait_flag(int tid, int* f, int tgt) {
    if (tid == 0)
        while (__hip_atomic_load(f, __ATOMIC_ACQUIRE, __HIP_MEMORY_SCOPE_AGENT) < tgt)
            __builtin_amdgcn_s_sleep(2);
    __syncthreads();
}

// ---------- GEMM task body: 256x256 tile, BK=64, 8-phase (T2+T3+T4+T5) ----
// Byte-identical schedule to the round-3/4 HW-verified kernel (886 TF @
// K=1024): 4 barriers/K-tile; counted vmcnt(6)/tile; tail tiles drain
// vmcnt(0). Stage per tile T: p0:(T+1).A1 p1:(T+2).A0 p2:(T+2).B0 p3:(T+2).B1.
// LDS swizzle (both-sides, rule #21): linear dest for global_load_lds, global
// SOURCE chunk pre-permuted chunk^=row&7, reads XOR byte^=((row&7)<<4).
// M=32768, N=K=1024, NT=16 hard-coded.

#define STAGE(GB, SLOT) \
    gload16((GB) + g0, (char*)(SLOT) + d0); \
    gload16((GB) + g1, (char*)(SLOT) + d1);

#define READ_A(SLOT) \
    _Pragma("unroll") for (int f = 0; f < 4; ++f) \
    _Pragma("unroll") for (int kk = 0; kk < 2; ++kk) \
        a[f][kk] = *(const bf16x8*)((const char*)(SLOT) + \
            (((rhA + f * 32) << 7) + (cA ^ (kk << 6))));

#define READ_B(SLOT, GB) \
    _Pragma("unroll") for (int g = 0; g < 2; ++g) \
    _Pragma("unroll") for (int kk = 0; kk < 2; ++kk) \
        b[(GB) + g][kk] = *(const bf16x8*)((const char*)(SLOT) + \
            (((rhB + g * 64) << 7) + (cB ^ (kk << 6))));

#define MFMA_QUAD(FB, GB) \
    __builtin_amdgcn_s_setprio(1); \
    _Pragma("unroll") for (int f = 0; f < 4; ++f) \
    _Pragma("unroll") for (int g = 0; g < 2; ++g) \
    _Pragma("unroll") for (int kk = 0; kk < 2; ++kk) \
        acc[(FB) + f][(GB) + g] = __builtin_amdgcn_mfma_f32_16x16x32_bf16( \
            a[f][kk], b[(GB) + g][kk], acc[(FB) + f][(GB) + g], 0, 0, 0); \
    __builtin_amdgcn_s_setprio(0);

#define TILE_BODY(T, BB, VMW) { \
    bf16x8 a[4][2], b[4][2]; \
    READ_A(lds[BB][0]); \
    READ_B(lds[BB][2], 0); \
    if ((T) + 1 < NT) { STAGE(A1p + ((T) + 1) * 64, lds[(BB) ^ 1][1]); } \
    MFMA_QUAD(0, 0); \
    S_BARRIER(); \
    READ_B(lds[BB][3], 2); \
    if ((T) + 2 < NT) { STAGE(A0p + ((T) + 2) * 64, lds[BB][0]); } \
    MFMA_QUAD(0, 2); \
    S_BARRIER(); \
    READ_A(lds[BB][1]); \
    if ((T) + 2 < NT) { STAGE(B0p + ((T) + 2) * 64, lds[BB][2]); } \
    MFMA_QUAD(4, 0); \
    S_BARRIER(); \
    if ((T) + 2 < NT) { STAGE(B1p + ((T) + 2) * 64, lds[BB][3]); } \
    MFMA_QUAD(4, 2); \
    asm volatile(VMW ::: "memory"); \
    S_BARRIER(); \
}

template <int ACC_SSQ, int HAS_SCALE, typename CT>
__device__ __forceinline__ void gemm_task(u16 (*lds)[4][8192],
                          const u16* __restrict__ A, const u16* __restrict__ Btb,
                          CT* __restrict__ C, float* __restrict__ ssq,
                          int* f_zero, int m0, int n0, int tid) {
    const int lane = tid & 63;
    const int w    = tid >> 6;
    const int wm   = w >> 2;          // 0..1
    const int wn   = w & 3;           // 0..3

    const u16* A0p = A   + (size_t)m0 * 1024;
    const u16* A1p = A0p + (size_t)128 * 1024;
    const u16* B0p = Btb + (size_t)n0 * 1024;
    const u16* B1p = B0p + (size_t)128 * 1024;

    const int    trow   = tid >> 3;
    const int    tchunk = (tid & 7) ^ (trow & 7);
    const size_t g0 = (size_t)trow * 1024 + (size_t)tchunk * 8;  // u16 elems
    const size_t g1 = g0 + (size_t)64 * 1024;
    const int    d0 = tid * 16;                                   // bytes
    const int    d1 = d0 + 8192;

    const int NT = 16;

    const int rm  = lane & 15;
    const int kqb = (lane >> 4) << 4;
    const int rhA = wm * 16 + rm;
    const int cA  = kqb ^ ((rhA & 7) << 4);
    const int rhB = wn * 16 + rm;
    const int cB  = kqb ^ ((rhB & 7) << 4);

    f32x4 acc[8][4] = {};

    // prologue: stage T0 fully + T1.{A0,B0,B1}; vmcnt(6) -> T0 landed
    STAGE(A0p + 0,  lds[0][0]);
    STAGE(B0p + 0,  lds[0][2]);
    STAGE(B1p + 0,  lds[0][3]);
    STAGE(A1p + 0,  lds[0][1]);
    STAGE(A0p + 64, lds[1][0]);
    STAGE(B0p + 64, lds[1][2]);
    STAGE(B1p + 64, lds[1][3]);
    asm volatile("s_waitcnt vmcnt(6)" ::: "memory");
    S_BARRIER();

    #pragma unroll 1
    for (int T = 0; T < NT - 2; T += 2) {
        TILE_BODY(T, 0, "s_waitcnt vmcnt(6)");
        TILE_BODY(T + 1, 1, "s_waitcnt vmcnt(6)");
    }
    TILE_BODY(NT - 2, 0, "s_waitcnt vmcnt(0)");
    TILE_BODY(NT - 1, 1, "s_waitcnt vmcnt(0)");

    // ---- epilogue ----  C/D: col=lane&15, row=(lane>>4)*4+reg [m89]
    __syncthreads();
    float* lred = (float*)&lds[0][0][0];   // 256 floats, LDS reuse
    if constexpr (HAS_SCALE) {
        if (tid < 256) {
            float q = ssq[m0 + tid];
            lred[tid] = 1.0f / fmaxf(sqrtf(q), 1e-12f);
        }
        __syncthreads();
    }
    if constexpr (ACC_SSQ) {
        if (tid < 256) lred[tid] = 0.f;
        __syncthreads();
    }
    const int cn = lane & 15;
    const int rq = (lane >> 4) * 4;
    #pragma unroll
    for (int f = 0; f < 8; ++f) {
        const int rbase = f * 32 + wm * 16 + rq;
        #pragma unroll
        for (int r = 0; r < 4; ++r) {
            const size_t rowoff = (size_t)(m0 + rbase + r) * 1024;
            float s = 0.f;
            #pragma unroll
            for (int g = 0; g < 4; ++g) {
                float x = acc[f][g][r];
                if constexpr (HAS_SCALE) x *= lred[rbase + r];
                if constexpr (ACC_SSQ) s += x * x;
                const int col = n0 + g * 64 + wn * 16 + cn;
                if constexpr (sizeof(CT) == 2) ((u16*)C)[rowoff + col] = f2bf(x);
                else                           C[rowoff + col] = x;
            }
            if constexpr (ACC_SSQ) {
                s += __shfl_xor(s, 1);
                s += __shfl_xor(s, 2);
                s += __shfl_xor(s, 4);
                s += __shfl_xor(s, 8);
                if (cn == 0) atomicAdd(&lred[rbase + r], s);  // 4 wn-waves/row
            }
        }
    }
    if constexpr (ACC_SSQ) {
        __syncthreads();
        // ssq zeroing ran as tasks; ensure it retired before global atomics
        wait_flag(tid, f_zero, 8);
        if (tid < 256) atomicAdd(&ssq[m0 + tid], lred[tid]);  // 4 n-blocks/row
    }
}

// ---------- fused1: prep + gemm1 in ONE persistent dispatch ----------
// 256 blocks x 512 threads, 1 block/CU (128 KiB LDS). Work-stealing counter;
// task order (1928 total):
//   [0,128)      transpose Wq -> WqT (64c x 128r tiles)
//   [128,136)    zero ssq
//   [136,1672)   interleave, 128 groups x 12: 8 cvt tasks (mt=g) then
//                4 gemm1 tiles (mt = g-8, wrapped: g<8 -> mt=120+g). The
//                lag-8 lets gemm1 start ~t=5us while cvt still streams.
//   [1672,1928)  w2t (tail: hides under the last gemm wave)
// Deadlock-free: pops totally ordered; gemm waits only on transpose/zero/cvt
// tasks (which never wait) popped strictly earlier -> producers resident or
// done. Co-residency NOT required for correctness.
__global__ __launch_bounds__(512, 1) void fused1(const float* __restrict__ h,
                                                 u16* __restrict__ hbf,
                                                 const float* __restrict__ Wq,
                                                 u16* __restrict__ WqT,
                                                 const float* __restrict__ M0,
                                                 const float* __restrict__ Wo,
                                                 u16* __restrict__ W2T,
                                                 float* __restrict__ ssq,
                                                 u16* __restrict__ P,
                                                 int* flags) {
    __shared__ u16 lds[2][4][8192];   // 128 KiB (prep tasks overlay low part)
    __shared__ int task_s;
    int* ctr    = flags + 0;
    int* f_wqt  = flags + 1;   // target 128
    int* f_zero = flags + 2;   // target 8
    int* f_cvt  = flags + 3;   // [128], target 8 each
    const int tid = threadIdx.x;

    for (;;) {
        if (tid == 0)
            task_s = __hip_atomic_fetch_add(ctr, 1, __ATOMIC_RELAXED,
                                            __HIP_MEMORY_SCOPE_AGENT);
        __syncthreads();
        const int task = task_s;
        __syncthreads();   // all threads read task_s before next overwrite
        if (task >= 1928) return;

        if (task < 128) {
            // ---- transpose: Wq [K][N] fp32 -> WqT [N][K] bf16 (64c x 128r) --
            const int c0 = (task & 15) * 64;
            const int r0 = (task >> 4) * 128;
            u16 (*tile)[65] = (u16 (*)[65])&lds[0][0][0];  // 128x65 = 16640 B
            const int col = tid & 63, rg = tid >> 6;       // rg 0..7
            #pragma unroll
            for (int rr = 0; rr < 16; ++rr)
                tile[rg * 16 + rr][col] =
                    f2bf(Wq[(size_t)(r0 + rg * 16 + rr) * 1024 + c0 + col]);
            __syncthreads();
            const int k = tid & 127, ng = tid >> 7;        // ng 0..3
            #pragma unroll
            for (int rr = 0; rr < 16; ++rr) {
                int n = c0 + ng * 16 + rr;
                WqT[(size_t)n * 1024 + r0 + k] = tile[k][ng * 16 + rr];
            }
            task_done(tid, f_wqt);
        } else if (task < 136) {
            // ---- zero ssq: 32768 floats over 8 tasks ----
            const int z = task - 128;
            #pragma unroll
            for (int it = 0; it < 2; ++it)
                ((f32x4*)ssq)[(size_t)z * 1024 + it * 512 + tid] =
                    f32x4{0.f, 0.f, 0.f, 0.f};
            task_done(tid, f_zero);
        } else if (task < 1672) {
            const int u = task - 136;
            const int g = u / 12, s = u % 12;
            if (s < 8) {
                // ---- cvt: h fp32 -> hbf bf16, 32 rows per task ----
                const int c = g * 8 + s;
                const size_t base = (size_t)c * 4096;   // 8-elem groups
                #pragma unroll
                for (int it = 0; it < 8; ++it) {
                    size_t i = base + (size_t)it * 512 + tid;
                    const f32x4* xp = (const f32x4*)h + i * 2;
                    f32x4 va = xp[0], vb = xp[1];
                    u16x8 o;
                    o[0]=f2bf(va[0]); o[1]=f2bf(va[1]); o[2]=f2bf(va[2]); o[3]=f2bf(va[3]);
                    o[4]=f2bf(vb[0]); o[5]=f2bf(vb[1]); o[6]=f2bf(vb[2]); o[7]=f2bf(vb[3]);
                    ((u16x8*)hbf)[i] = o;
                }
                task_done(tid, &f_cvt[g]);
            } else {
                // ---- gemm1 tile: mt lagged 8 groups behind its cvt ----
                const int mt = (g >= 8) ? (g - 8) : (120 + g);
                const int n0 = (s - 8) << 8;
                wait_flag(tid, f_wqt, 128);
                wait_flag(tid, &f_cvt[mt], 8);
                gemm_task<1, 0, u16>(lds, hbf, WqT, P, ssq, f_zero,
                                     mt << 8, n0, tid);
            }
        } else {
            // ---- w2t: W2T[b][j][h*64+d] = sum_e M0[b,h,d,e]*Wo[h*64+e][j] --
            const int wt = task - 1672;
            const int jq = wt & 3, hh = (wt >> 2) & 15, b = wt >> 6;
            float* m0s = (float*)&lds[0][0][0];                       // 16 KB
            u16 (*outs)[66] = (u16 (*)[66])((char*)&lds[0][0][0] + 16384);
            const float* m0p = M0 + ((size_t)b * 16 + hh) * 4096;
            for (int i = tid; i < 4096; i += 512) m0s[i] = m0p[i];
            __syncthreads();
            {
                const int jj = tid >> 1, half = tid & 1;
                const int j = jq * 256 + jj;
                float wo[64];
                #pragma unroll
                for (int e = 0; e < 64; ++e)
                    wo[e] = Wo[(size_t)(hh * 64 + e) * 1024 + j];
                #pragma unroll 1
                for (int d = half * 32; d < half * 32 + 32; ++d) {
                    float sv = 0.f;
                    #pragma unroll
                    for (int e = 0; e < 64; ++e) sv += m0s[d * 64 + e] * wo[e];
                    outs[jj][d] = f2bf(sv);
                }
            }
            __syncthreads();
            const int d = tid & 63, jr = tid >> 6;   // jr 0..7
            u16* wp = W2T + (size_t)b * 1048576 +
                      (size_t)(jq * 256) * 1024 + hh * 64 + d;
            #pragma unroll 1
            for (int it = 0; it < 32; ++it) {
                int jl = it * 8 + jr;
                wp[(size_t)jl * 1024] = outs[jl][d];
            }
            // no flag needed: dispatch boundary orders w2t before gemm2
        }
    }
}

// ---------- dispatch 2: gemm2 (round-4 verified kernel, XCD swizzle) -------
__global__ __launch_bounds__(512) void gemm2k(const u16* __restrict__ A,
                                              const u16* __restrict__ Bt,
                                              float* __restrict__ C,
                                              float* __restrict__ ssq) {
    __shared__ u16 lds[2][4][8192];
    // XCD-aware swizzle: 4 n-tiles of an m-tile share one XCD's L2.
    const int id  = blockIdx.x;
    const int xcd = id & 7;
    const int loc = id >> 3;
    const int mt  = xcd * 16 + (loc >> 2);
    const int ntt = loc & 3;
    const u16* Btb = Bt + (size_t)(mt >> 5) * 1048576;   // batch = m0>>13
    gemm_task<0, 1, float>(lds, A, Btb, C, ssq, nullptr,
                           mt << 8, ntt << 8, (int)threadIdx.x);
}

// ---------- launch ----------
// B=4, S=8192, HID=PROJ=1024, NH=16, HD=64; M = B*S = 32768
// ws usage: 77,725,696 B — EXACTLY the round-0..4 proven footprint (round-5's
// failure is attributed to exceeding it). hbf lives in d_out's first half
// (dead after fused1; gemm2k overwrites all of d_out — stream-ordered, safe).
// flags live in d_out's SECOND half (untouched by cvt/gemm1; re-zeroed per
// iteration by our memset; overwritten by gemm2k after they're dead).
extern "C" void kernel_launch(void* const* d_in, const int* in_sizes, int n_in,
                              void* d_out, int out_size, void* d_ws, size_t ws_size,
                              hipStream_t stream) {
    const float* h  = (const float*)d_in[0];   // [4,8192,1024]
    const float* Wq = (const float*)d_in[1];   // [1024,1024]
    const float* Wo = (const float*)d_in[7];   // [1024,1024]
    const float* M0 = (const float*)d_in[8];   // [4,16,64,64]
    float* out = (float*)d_out;

    char* ws = (char*)d_ws;
    u16*   hbf  = (u16*)d_out;                 // 67,108,864 B (first half of out)
    int*   flags= (int*)((char*)d_out + 67108864);  // 524 B in out's 2nd half
    u16*   P    = (u16*)(ws);                  // 67,108,864 B
    u16*   WqT  = (u16*)(ws + 67108864);       //  2,097,152 B
    u16*   W2T  = (u16*)(ws + 69206016);       //  8,388,608 B
    float* ssq  = (float*)(ws + 77594624);     //    131,072 B  (end: 77,725,696)

    hipMemsetAsync(flags, 0, 524, stream);     // graph-capture-safe
    // fused prep + gemm1 (work-stealing, cvt/gemm interleaved lag-8)
    fused1<<<256, 512, 0, stream>>>(h, hbf, Wq, WqT, M0, Wo, W2T, ssq, P, flags);
    // out = (1/max(sqrt(ssq),1e-12))[m] * (P @ W2T[batch]) ; batch = m >> 13
    gemm2k<<<512, 512, 0, stream>>>(P, W2T, out, ssq);
}

// Round 7
// 385.615 us; speedup vs baseline: 1.5772x; 1.5772x over previous
//
#include <hip/hip_runtime.h>

typedef unsigned short u16;
typedef __bf16 bf16x8 __attribute__((ext_vector_type(8)));
typedef float   f32x4 __attribute__((ext_vector_type(4)));
typedef unsigned short u16x8 __attribute__((ext_vector_type(8)));

// ---------- helpers ----------
__device__ __forceinline__ u16 f2bf(float f) {
    unsigned int u = __builtin_bit_cast(unsigned int, f);
    u = u + 0x7FFFu + ((u >> 16) & 1u);   // round-to-nearest-even
    return (u16)(u >> 16);
}
__device__ __forceinline__ void gload16(const void* g, void* l) {
    __builtin_amdgcn_global_load_lds(
        (__attribute__((address_space(1))) void*)g,
        (__attribute__((address_space(3))) void*)l,
        16, 0, 0);
}

#define S_BARRIER() asm volatile("s_barrier" ::: "memory")

// ---------- fused prep: w2t | transpose | ssq-zero | cvt in ONE dispatch ----
// One grid: blocks [0,256) build W2T, [256,512) transpose Wq, [512,544) zero
// ssq, [544,16928) cast h->bf16. Small jobs at low indices dispatch first and
// hide entirely under the 32-us cvt stream. LDS: 50176-B union -> 3 blocks/CU,
// 12 waves/CU — enough in-flight loads for cvt to hold HBM BW (round-6 lesson:
// 1 block/CU persistent residency caps streaming at ~1.2 TB/s).
__global__ __launch_bounds__(256) void prep(const float* __restrict__ h,
                                            u16* __restrict__ hbf,
                                            const float* __restrict__ Wq,
                                            u16* __restrict__ WqT,
                                            const float* __restrict__ M0,
                                            const float* __restrict__ Wo,
                                            u16* __restrict__ W2T,
                                            float* __restrict__ ssq) {
    __shared__ __align__(16) char smem[50176];
    const int bid = blockIdx.x;
    const int tid = threadIdx.x;

    if (bid < 256) {
        // ---- build_w2t: W2T[b][j][h*64+d] = sum_e M0[b,h,d,e]*Wo[h*64+e][j]
        // (results staged in padded LDS, written with lane=d -> 128 B-contig)
        float* m0s = (float*)smem;
        u16 (*outs)[66] = (u16 (*)[66])(smem + 16384);
        const int jq = bid & 3, hh = (bid >> 2) & 15, b = bid >> 6;
        const int j = jq * 256 + tid;
        const float* m0p = M0 + ((size_t)b * 16 + hh) * 4096;
        for (int i = tid; i < 4096; i += 256) m0s[i] = m0p[i];
        __syncthreads();
        float wo[64];
        #pragma unroll
        for (int e = 0; e < 64; ++e) wo[e] = Wo[(size_t)(hh * 64 + e) * 1024 + j];
        #pragma unroll 1
        for (int d = 0; d < 64; ++d) {
            float s = 0.f;
            #pragma unroll
            for (int e = 0; e < 64; ++e) s += m0s[d * 64 + e] * wo[e];
            outs[tid][d] = f2bf(s);
        }
        __syncthreads();
        const int d = tid & 63, jr = tid >> 6;
        u16* wp = W2T + (size_t)b * 1024 * 1024 + (size_t)(jq * 256) * 1024 + hh * 64 + d;
        #pragma unroll 1
        for (int it = 0; it < 64; ++it) {
            int jl = it * 4 + jr;
            wp[(size_t)jl * 1024] = outs[jl][d];
        }
    } else if (bid < 512) {
        // ---- transpose_cvt: Wq [K][N] fp32 -> WqT [N][K] bf16 ----
        u16 (*tile)[65] = (u16 (*)[65])smem;
        const int bb = bid - 256;
        const int c0 = (bb & 15) * 64;
        const int r0 = (bb >> 4) * 64;
        const int col = tid & 63;
        const int rb  = (tid >> 6) * 16;
        #pragma unroll
        for (int rr = 0; rr < 16; ++rr)
            tile[rb + rr][col] = f2bf(Wq[(size_t)(r0 + rb + rr) * 1024 + c0 + col]);
        __syncthreads();
        const int k = tid & 63;
        #pragma unroll
        for (int rr = 0; rr < 16; ++rr) {
            int n = c0 + rb + rr;
            WqT[(size_t)n * 1024 + r0 + k] = tile[k][rb + rr];
        }
    } else if (bid < 544) {
        // ---- ssq zero: 32768 floats across 32 blocks ----
        ((f32x4*)ssq)[(size_t)(bid - 512) * 256 + tid] = f32x4{0.f, 0.f, 0.f, 0.f};
    } else {
        // ---- cvt_bf16: h fp32 -> bf16, 8 elems/thread ----
        const int i = (bid - 544) * 256 + tid;
        if (i >= 4194304) return;
        const f32x4* xp = (const f32x4*)h + (size_t)i * 2;
        f32x4 a = xp[0], c = xp[1];
        u16x8 o;
        o[0]=f2bf(a[0]); o[1]=f2bf(a[1]); o[2]=f2bf(a[2]); o[3]=f2bf(a[3]);
        o[4]=f2bf(c[0]); o[5]=f2bf(c[1]); o[6]=f2bf(c[2]); o[7]=f2bf(c[3]);
        ((u16x8*)hbf)[i] = o;
    }
}

// ---------- GEMM: 256x256 tile, BK=64, 8-phase (T2+T3+T4+T5) ----------
// C[M,N] = A[M,K] * Bt[N,K]^T, bf16 in, fp32 acc.  (round-3/4 verified body,
// 886 TF @ K=1024 = plain-HIP 8-phase template ceiling for this shape.)
// 4 barriers/K-tile; counted vmcnt(6) per tile; tail tiles drain vmcnt(0).
// Stage schedule per tile T: p0:(T+1).A1  p1:(T+2).A0  p2:(T+2).B0
// p3:(T+2).B1 + vmcnt(6) (retires all of tile T+1; 6 = 3 half-tiles left).
// LDS swizzle (both-sides, rule #21): linear dest for global_load_lds, global
// SOURCE chunk pre-permuted chunk^=row&7, reads XOR byte^=((row&7)<<4).
// Grid 512 = 128 m-tiles x 4 n-tiles; xcd=id&7, all 4 n-tiles of an m-tile
// on one XCD (A panel L2-resident; 512%8==0 bijective).

#define STAGE(GB, SLOT) \
    gload16((GB) + g0, (char*)(SLOT) + d0); \
    gload16((GB) + g1, (char*)(SLOT) + d1);

#define READ_A(SLOT) \
    _Pragma("unroll") for (int f = 0; f < 4; ++f) \
    _Pragma("unroll") for (int kk = 0; kk < 2; ++kk) \
        a[f][kk] = *(const bf16x8*)((const char*)(SLOT) + \
            (((rhA + f * 32) << 7) + (cA ^ (kk << 6))));

#define READ_B(SLOT, GB) \
    _Pragma("unroll") for (int g = 0; g < 2; ++g) \
    _Pragma("unroll") for (int kk = 0; kk < 2; ++kk) \
        b[(GB) + g][kk] = *(const bf16x8*)((const char*)(SLOT) + \
            (((rhB + g * 64) << 7) + (cB ^ (kk << 6))));

#define MFMA_QUAD(FB, GB) \
    __builtin_amdgcn_s_setprio(1); \
    _Pragma("unroll") for (int f = 0; f < 4; ++f) \
    _Pragma("unroll") for (int g = 0; g < 2; ++g) \
    _Pragma("unroll") for (int kk = 0; kk < 2; ++kk) \
        acc[(FB) + f][(GB) + g] = __builtin_amdgcn_mfma_f32_16x16x32_bf16( \
            a[f][kk], b[(GB) + g][kk], acc[(FB) + f][(GB) + g], 0, 0, 0); \
    __builtin_amdgcn_s_setprio(0);

#define TILE_BODY(T, BB, VMW) { \
    bf16x8 a[4][2], b[4][2]; \
    /* p0: reads a0,b01(T); stage (T+1).A1 (slot's old a1(T-1) read done   */ \
    /* before T-1.p2's barrier).                                           */ \
    READ_A(lds[BB][0]); \
    READ_B(lds[BB][2], 0); \
    if ((T) + 1 < NT) { STAGE(A1p + ((T) + 1) * 64, lds[(BB) ^ 1][1]); } \
    MFMA_QUAD(0, 0); \
    S_BARRIER(); \
    /* p1: reads b23(T); stage (T+2).A0 over a0(T) (reads done < p0 bar). */ \
    READ_B(lds[BB][3], 2); \
    if ((T) + 2 < NT) { STAGE(A0p + ((T) + 2) * 64, lds[BB][0]); } \
    MFMA_QUAD(0, 2); \
    S_BARRIER(); \
    /* p2: reads a1(T); stage (T+2).B0 over b01(T) (reads done < p0 bar). */ \
    READ_A(lds[BB][1]); \
    if ((T) + 2 < NT) { STAGE(B0p + ((T) + 2) * 64, lds[BB][2]); } \
    MFMA_QUAD(4, 0); \
    S_BARRIER(); \
    /* p3: stage (T+2).B1 over b23(T) (reads done < p1 bar); counted vmcnt */ \
    /* publishes tile T+1 for next p0.                                     */ \
    if ((T) + 2 < NT) { STAGE(B1p + ((T) + 2) * 64, lds[BB][3]); } \
    MFMA_QUAD(4, 2); \
    asm volatile(VMW ::: "memory"); \
    S_BARRIER(); \
}

template <int ACC_SSQ, int HAS_SCALE, typename CT>
__global__ __launch_bounds__(512) void gemm256_8ph(const u16* __restrict__ A,
                                                   const u16* __restrict__ Bt,
                                                   CT* __restrict__ C,
                                                   float* __restrict__ ssq,
                                                   int M, int N, int K,
                                                   long long bt_batch_stride,
                                                   int rpb_log2) {
    __shared__ u16 lds[2][4][8192];   // 128 KiB
    const int tid  = threadIdx.x;
    const int lane = tid & 63;
    const int w    = tid >> 6;
    const int wm   = w >> 2;          // 0..1
    const int wn   = w & 3;           // 0..3

    // XCD-aware swizzle: 4 n-tiles of an m-tile share one XCD's L2.
    const int id  = blockIdx.x;
    const int xcd = id & 7;
    const int loc = id >> 3;
    const int mpx = (M >> 8) >> 3;            // m-tiles per XCD (16)
    const int mt  = xcd * mpx + (loc >> 2);
    const int ntt = loc & 3;
    const int m0  = mt << 8;
    const int n0  = ntt << 8;

    const u16* Btb = Bt + (size_t)(m0 >> rpb_log2) * (size_t)bt_batch_stride;
    const u16* A0p = A   + (size_t)m0 * K;
    const u16* A1p = A0p + (size_t)128 * K;
    const u16* B0p = Btb + (size_t)n0 * K;
    const u16* B1p = B0p + (size_t)128 * K;

    // staging: thread t loads rows (t>>3) and 64+(t>>3); source chunk
    // pre-swizzled so linear LDS + swizzled read is consistent (involution).
    const int    trow   = tid >> 3;
    const int    tchunk = (tid & 7) ^ (trow & 7);
    const size_t g0 = (size_t)trow * K + (size_t)tchunk * 8;   // u16 elems
    const size_t g1 = g0 + (size_t)64 * K;
    const int    d0 = tid * 16;                                 // bytes
    const int    d1 = d0 + 8192;

    const int NT = K >> 6;    // K-tiles (16); NT even, NT >= 4 assumed

    // per-lane LDS read bases (swizzle XOR constant per lane)
    const int rm  = lane & 15;
    const int kqb = (lane >> 4) << 4;                // byte offset of kq
    const int rhA = wm * 16 + rm;
    const int cA  = kqb ^ ((rhA & 7) << 4);
    const int rhB = wn * 16 + rm;
    const int cB  = kqb ^ ((rhB & 7) << 4);

    f32x4 acc[8][4] = {};

    // ---- prologue: stage T0 fully + T1.{A0,B0,B1}; vmcnt(6) -> T0 landed ----
    STAGE(A0p + 0,  lds[0][0]);
    STAGE(B0p + 0,  lds[0][2]);
    STAGE(B1p + 0,  lds[0][3]);
    STAGE(A1p + 0,  lds[0][1]);
    STAGE(A0p + 64, lds[1][0]);
    STAGE(B0p + 64, lds[1][2]);
    STAGE(B1p + 64, lds[1][3]);
    asm volatile("s_waitcnt vmcnt(6)" ::: "memory");
    S_BARRIER();

    #pragma unroll 1
    for (int T = 0; T < NT - 2; T += 2) {
        TILE_BODY(T, 0, "s_waitcnt vmcnt(6)");
        TILE_BODY(T + 1, 1, "s_waitcnt vmcnt(6)");
    }
    // tail: vmcnt(6) at NT-2.p3 would only prove A0(NT-1) landed; drain fully.
    TILE_BODY(NT - 2, 0, "s_waitcnt vmcnt(0)");
    TILE_BODY(NT - 1, 1, "s_waitcnt vmcnt(0)");

    // ---- epilogue ----  C/D: col=lane&15, row=(lane>>4)*4+reg [m89]
    __syncthreads();
    float* lred = (float*)&lds[0][0][0];   // 256 floats, LDS reuse
    if constexpr (HAS_SCALE) {
        if (tid < 256) {
            float q = ssq[m0 + tid];
            lred[tid] = 1.0f / fmaxf(sqrtf(q), 1e-12f);
        }
        __syncthreads();
    }
    if constexpr (ACC_SSQ) {
        if (tid < 256) lred[tid] = 0.f;
        __syncthreads();
    }
    const int cn = lane & 15;
    const int rq = (lane >> 4) * 4;
    #pragma unroll
    for (int f = 0; f < 8; ++f) {
        const int rbase = f * 32 + wm * 16 + rq;
        #pragma unroll
        for (int r = 0; r < 4; ++r) {
            const size_t rowoff = (size_t)(m0 + rbase + r) * N;
            float s = 0.f;
            #pragma unroll
            for (int g = 0; g < 4; ++g) {
                float x = acc[f][g][r];
                if constexpr (HAS_SCALE) x *= lred[rbase + r];
                if constexpr (ACC_SSQ) s += x * x;
                const int col = n0 + g * 64 + wn * 16 + cn;
                if constexpr (sizeof(CT) == 2) ((u16*)C)[rowoff + col] = f2bf(x);
                else                           C[rowoff + col] = x;
            }
            if constexpr (ACC_SSQ) {
                s += __shfl_xor(s, 1);
                s += __shfl_xor(s, 2);
                s += __shfl_xor(s, 4);
                s += __shfl_xor(s, 8);
                if (cn == 0) atomicAdd(&lred[rbase + r], s);  // 4 wn-waves/row
            }
        }
    }
    if constexpr (ACC_SSQ) {
        __syncthreads();
        if (tid < 256) atomicAdd(&ssq[m0 + tid], lred[tid]);  // 4 n-blocks/row
    }
}

// ---------- launch ----------
// B=4, S=8192, HID=PROJ=1024, NH=16, HD=64; M = B*S = 32768
// ws usage: 77.7 MiB (proven footprint). hbf lives in d_out's first half
// (dead after gemm1; gemm2 overwrites all of d_out — stream-ordered, safe).
extern "C" void kernel_launch(void* const* d_in, const int* in_sizes, int n_in,
                              void* d_out, int out_size, void* d_ws, size_t ws_size,
                              hipStream_t stream) {
    const float* h  = (const float*)d_in[0];   // [4,8192,1024]
    const float* Wq = (const float*)d_in[1];   // [1024,1024]
    const float* Wo = (const float*)d_in[7];   // [1024,1024]
    const float* M0 = (const float*)d_in[8];   // [4,16,64,64]
    float* out = (float*)d_out;

    char* ws = (char*)d_ws;
    u16*   hbf  = (u16*)d_out;                 // 67,108,864 B (first half of out)
    u16*   P    = (u16*)(ws);                  // 67,108,864 B
    u16*   WqT  = (u16*)(ws + 67108864);       //  2,097,152 B
    u16*   W2T  = (u16*)(ws + 69206016);       //  8,388,608 B
    float* ssq  = (float*)(ws + 77594624);     //    131,072 B  (end: 77,725,696)

    const int M = 32768, N = 1024, K = 1024;

    // one fused prep dispatch: w2t(256) | transpose(256) | ssq-zero(32) | cvt(16384)
    prep<<<16928, 256, 0, stream>>>(h, hbf, Wq, WqT, M0, Wo, W2T, ssq);
    // P = h @ Wq (bf16, un-normalized) + per-row ssq via atomics
    gemm256_8ph<1, 0, u16><<<512, 512, 0, stream>>>(
        hbf, WqT, P, ssq, M, N, K, 0, 0);
    // out = (1/max(sqrt(ssq),1e-12))[m] * (P @ W2T[batch]) ; batch = m >> 13
    gemm256_8ph<0, 1, float><<<512, 512, 0, stream>>>(
        P, W2T, out, ssq, M, N, K, (long long)1024 * 1024, 13);
}

// Round 8
// 379.764 us; speedup vs baseline: 1.6015x; 1.0154x over previous
//
#include <hip/hip_runtime.h>

typedef unsigned short u16;
typedef __bf16 bf16x8 __attribute__((ext_vector_type(8)));
typedef float   f32x4 __attribute__((ext_vector_type(4)));
typedef unsigned short u16x8 __attribute__((ext_vector_type(8)));

// ---------- helpers ----------
__device__ __forceinline__ u16 f2bf(float f) {
    unsigned int u = __builtin_bit_cast(unsigned int, f);
    u = u + 0x7FFFu + ((u >> 16) & 1u);   // round-to-nearest-even
    return (u16)(u >> 16);
}
__device__ __forceinline__ void gload16(const void* g, void* l) {
    __builtin_amdgcn_global_load_lds(
        (__attribute__((address_space(1))) void*)g,
        (__attribute__((address_space(3))) void*)l,
        16, 0, 0);
}

#define S_BARRIER() asm volatile("s_barrier" ::: "memory")

// ---------- fused prep: w2t | transpose | ssq-zero | cvt in ONE dispatch ----
// Blocks [0,256) build W2T, [256,512) transpose Wq, [512,544) zero ssq,
// [544,16928) cast h->bf16. Small jobs at low indices hide under the cvt
// stream. 3 blocks/CU (50 KiB LDS union) keeps cvt at HBM BW.
// NT policy: h and Wq are single-use streams -> nontemporal loads, so the
// hbf/WqT outputs (gemm1's inputs) stay L3-resident. Round-7 counters showed
// gemm1 re-fetching 50 MB of hbf from HBM when h's streaming reads evicted it.
__global__ __launch_bounds__(256) void prep(const float* __restrict__ h,
                                            u16* __restrict__ hbf,
                                            const float* __restrict__ Wq,
                                            u16* __restrict__ WqT,
                                            const float* __restrict__ M0,
                                            const float* __restrict__ Wo,
                                            u16* __restrict__ W2T,
                                            float* __restrict__ ssq) {
    __shared__ __align__(16) char smem[50176];
    const int bid = blockIdx.x;
    const int tid = threadIdx.x;

    if (bid < 256) {
        // ---- build_w2t: W2T[b][j][h*64+d] = sum_e M0[b,h,d,e]*Wo[h*64+e][j]
        // (results staged in padded LDS, written with lane=d -> 128 B-contig)
        float* m0s = (float*)smem;
        u16 (*outs)[66] = (u16 (*)[66])(smem + 16384);
        const int jq = bid & 3, hh = (bid >> 2) & 15, b = bid >> 6;
        const int j = jq * 256 + tid;
        const float* m0p = M0 + ((size_t)b * 16 + hh) * 4096;
        for (int i = tid; i < 4096; i += 256) m0s[i] = m0p[i];
        __syncthreads();
        float wo[64];
        #pragma unroll
        for (int e = 0; e < 64; ++e) wo[e] = Wo[(size_t)(hh * 64 + e) * 1024 + j];
        #pragma unroll 1
        for (int d = 0; d < 64; ++d) {
            float s = 0.f;
            #pragma unroll
            for (int e = 0; e < 64; ++e) s += m0s[d * 64 + e] * wo[e];
            outs[tid][d] = f2bf(s);
        }
        __syncthreads();
        const int d = tid & 63, jr = tid >> 6;
        u16* wp = W2T + (size_t)b * 1024 * 1024 + (size_t)(jq * 256) * 1024 + hh * 64 + d;
        #pragma unroll 1
        for (int it = 0; it < 64; ++it) {
            int jl = it * 4 + jr;
            wp[(size_t)jl * 1024] = outs[jl][d];
        }
    } else if (bid < 512) {
        // ---- transpose_cvt: Wq [K][N] fp32 -> WqT [N][K] bf16 (nt loads) ----
        u16 (*tile)[65] = (u16 (*)[65])smem;
        const int bb = bid - 256;
        const int c0 = (bb & 15) * 64;
        const int r0 = (bb >> 4) * 64;
        const int col = tid & 63;
        const int rb  = (tid >> 6) * 16;
        #pragma unroll
        for (int rr = 0; rr < 16; ++rr)
            tile[rb + rr][col] = f2bf(__builtin_nontemporal_load(
                &Wq[(size_t)(r0 + rb + rr) * 1024 + c0 + col]));
        __syncthreads();
        const int k = tid & 63;
        #pragma unroll
        for (int rr = 0; rr < 16; ++rr) {
            int n = c0 + rb + rr;
            WqT[(size_t)n * 1024 + r0 + k] = tile[k][rb + rr];
        }
    } else if (bid < 544) {
        // ---- ssq zero: 32768 floats across 32 blocks ----
        ((f32x4*)ssq)[(size_t)(bid - 512) * 256 + tid] = f32x4{0.f, 0.f, 0.f, 0.f};
    } else {
        // ---- cvt_bf16: h fp32 -> bf16, 8 elems/thread (nt loads on h) ----
        const int i = (bid - 544) * 256 + tid;
        if (i >= 4194304) return;
        const f32x4* xp = (const f32x4*)h + (size_t)i * 2;
        f32x4 a = __builtin_nontemporal_load(xp);
        f32x4 c = __builtin_nontemporal_load(xp + 1);
        u16x8 o;
        o[0]=f2bf(a[0]); o[1]=f2bf(a[1]); o[2]=f2bf(a[2]); o[3]=f2bf(a[3]);
        o[4]=f2bf(c[0]); o[5]=f2bf(c[1]); o[6]=f2bf(c[2]); o[7]=f2bf(c[3]);
        ((u16x8*)hbf)[i] = o;
    }
}

// ---------- GEMM: 256x256 tile, BK=64, 8-phase (T2+T3+T4+T5) ----------
// C[M,N] = A[M,K] * Bt[N,K]^T, bf16 in, fp32 acc.  (round-3/4 verified body,
// 886 TF @ K=1024 = plain-HIP 8-phase template ceiling for this shape.)
// 4 barriers/K-tile; counted vmcnt(6) per tile; tail tiles drain vmcnt(0).
// Stage schedule per tile T: p0:(T+1).A1  p1:(T+2).A0  p2:(T+2).B0
// p3:(T+2).B1 + vmcnt(6) (retires all of tile T+1; 6 = 3 half-tiles left).
// LDS swizzle (both-sides, rule #21): linear dest for global_load_lds, global
// SOURCE chunk pre-permuted chunk^=row&7, reads XOR byte^=((row&7)<<4).
// Grid 512 = 128 m-tiles x 4 n-tiles; xcd=id&7, all 4 n-tiles of an m-tile
// on one XCD (A panel L2-resident; 512%8==0 bijective).
// NEW: fp32 C-writes (gemm2's `out`, 128 MB, never re-read) go nontemporal so
// they don't write-allocate L3 and evict the P/W2T panels gemm2 is reading.

#define STAGE(GB, SLOT) \
    gload16((GB) + g0, (char*)(SLOT) + d0); \
    gload16((GB) + g1, (char*)(SLOT) + d1);

#define READ_A(SLOT) \
    _Pragma("unroll") for (int f = 0; f < 4; ++f) \
    _Pragma("unroll") for (int kk = 0; kk < 2; ++kk) \
        a[f][kk] = *(const bf16x8*)((const char*)(SLOT) + \
            (((rhA + f * 32) << 7) + (cA ^ (kk << 6))));

#define READ_B(SLOT, GB) \
    _Pragma("unroll") for (int g = 0; g < 2; ++g) \
    _Pragma("unroll") for (int kk = 0; kk < 2; ++kk) \
        b[(GB) + g][kk] = *(const bf16x8*)((const char*)(SLOT) + \
            (((rhB + g * 64) << 7) + (cB ^ (kk << 6))));

#define MFMA_QUAD(FB, GB) \
    __builtin_amdgcn_s_setprio(1); \
    _Pragma("unroll") for (int f = 0; f < 4; ++f) \
    _Pragma("unroll") for (int g = 0; g < 2; ++g) \
    _Pragma("unroll") for (int kk = 0; kk < 2; ++kk) \
        acc[(FB) + f][(GB) + g] = __builtin_amdgcn_mfma_f32_16x16x32_bf16( \
            a[f][kk], b[(GB) + g][kk], acc[(FB) + f][(GB) + g], 0, 0, 0); \
    __builtin_amdgcn_s_setprio(0);

#define TILE_BODY(T, BB, VMW) { \
    bf16x8 a[4][2], b[4][2]; \
    /* p0: reads a0,b01(T); stage (T+1).A1 (slot's old a1(T-1) read done   */ \
    /* before T-1.p2's barrier).                                           */ \
    READ_A(lds[BB][0]); \
    READ_B(lds[BB][2], 0); \
    if ((T) + 1 < NT) { STAGE(A1p + ((T) + 1) * 64, lds[(BB) ^ 1][1]); } \
    MFMA_QUAD(0, 0); \
    S_BARRIER(); \
    /* p1: reads b23(T); stage (T+2).A0 over a0(T) (reads done < p0 bar). */ \
    READ_B(lds[BB][3], 2); \
    if ((T) + 2 < NT) { STAGE(A0p + ((T) + 2) * 64, lds[BB][0]); } \
    MFMA_QUAD(0, 2); \
    S_BARRIER(); \
    /* p2: reads a1(T); stage (T+2).B0 over b01(T) (reads done < p0 bar). */ \
    READ_A(lds[BB][1]); \
    if ((T) + 2 < NT) { STAGE(B0p + ((T) + 2) * 64, lds[BB][2]); } \
    MFMA_QUAD(4, 0); \
    S_BARRIER(); \
    /* p3: stage (T+2).B1 over b23(T) (reads done < p1 bar); counted vmcnt */ \
    /* publishes tile T+1 for next p0.                                     */ \
    if ((T) + 2 < NT) { STAGE(B1p + ((T) + 2) * 64, lds[BB][3]); } \
    MFMA_QUAD(4, 2); \
    asm volatile(VMW ::: "memory"); \
    S_BARRIER(); \
}

template <int ACC_SSQ, int HAS_SCALE, typename CT>
__global__ __launch_bounds__(512) void gemm256_8ph(const u16* __restrict__ A,
                                                   const u16* __restrict__ Bt,
                                                   CT* __restrict__ C,
                                                   float* __restrict__ ssq,
                                                   int M, int N, int K,
                                                   long long bt_batch_stride,
                                                   int rpb_log2) {
    __shared__ u16 lds[2][4][8192];   // 128 KiB
    const int tid  = threadIdx.x;
    const int lane = tid & 63;
    const int w    = tid >> 6;
    const int wm   = w >> 2;          // 0..1
    const int wn   = w & 3;           // 0..3

    // XCD-aware swizzle: 4 n-tiles of an m-tile share one XCD's L2.
    const int id  = blockIdx.x;
    const int xcd = id & 7;
    const int loc = id >> 3;
    const int mpx = (M >> 8) >> 3;            // m-tiles per XCD (16)
    const int mt  = xcd * mpx + (loc >> 2);
    const int ntt = loc & 3;
    const int m0  = mt << 8;
    const int n0  = ntt << 8;

    const u16* Btb = Bt + (size_t)(m0 >> rpb_log2) * (size_t)bt_batch_stride;
    const u16* A0p = A   + (size_t)m0 * K;
    const u16* A1p = A0p + (size_t)128 * K;
    const u16* B0p = Btb + (size_t)n0 * K;
    const u16* B1p = B0p + (size_t)128 * K;

    // staging: thread t loads rows (t>>3) and 64+(t>>3); source chunk
    // pre-swizzled so linear LDS + swizzled read is consistent (involution).
    const int    trow   = tid >> 3;
    const int    tchunk = (tid & 7) ^ (trow & 7);
    const size_t g0 = (size_t)trow * K + (size_t)tchunk * 8;   // u16 elems
    const size_t g1 = g0 + (size_t)64 * K;
    const int    d0 = tid * 16;                                 // bytes
    const int    d1 = d0 + 8192;

    const int NT = K >> 6;    // K-tiles (16); NT even, NT >= 4 assumed

    // per-lane LDS read bases (swizzle XOR constant per lane)
    const int rm  = lane & 15;
    const int kqb = (lane >> 4) << 4;                // byte offset of kq
    const int rhA = wm * 16 + rm;
    const int cA  = kqb ^ ((rhA & 7) << 4);
    const int rhB = wn * 16 + rm;
    const int cB  = kqb ^ ((rhB & 7) << 4);

    f32x4 acc[8][4] = {};

    // ---- prologue: stage T0 fully + T1.{A0,B0,B1}; vmcnt(6) -> T0 landed ----
    STAGE(A0p + 0,  lds[0][0]);
    STAGE(B0p + 0,  lds[0][2]);
    STAGE(B1p + 0,  lds[0][3]);
    STAGE(A1p + 0,  lds[0][1]);
    STAGE(A0p + 64, lds[1][0]);
    STAGE(B0p + 64, lds[1][2]);
    STAGE(B1p + 64, lds[1][3]);
    asm volatile("s_waitcnt vmcnt(6)" ::: "memory");
    S_BARRIER();

    #pragma unroll 1
    for (int T = 0; T < NT - 2; T += 2) {
        TILE_BODY(T, 0, "s_waitcnt vmcnt(6)");
        TILE_BODY(T + 1, 1, "s_waitcnt vmcnt(6)");
    }
    // tail: vmcnt(6) at NT-2.p3 would only prove A0(NT-1) landed; drain fully.
    TILE_BODY(NT - 2, 0, "s_waitcnt vmcnt(0)");
    TILE_BODY(NT - 1, 1, "s_waitcnt vmcnt(0)");

    // ---- epilogue ----  C/D: col=lane&15, row=(lane>>4)*4+reg [m89]
    __syncthreads();
    float* lred = (float*)&lds[0][0][0];   // 256 floats, LDS reuse
    if constexpr (HAS_SCALE) {
        if (tid < 256) {
            float q = ssq[m0 + tid];
            lred[tid] = 1.0f / fmaxf(sqrtf(q), 1e-12f);
        }
        __syncthreads();
    }
    if constexpr (ACC_SSQ) {
        if (tid < 256) lred[tid] = 0.f;
        __syncthreads();
    }
    const int cn = lane & 15;
    const int rq = (lane >> 4) * 4;
    #pragma unroll
    for (int f = 0; f < 8; ++f) {
        const int rbase = f * 32 + wm * 16 + rq;
        #pragma unroll
        for (int r = 0; r < 4; ++r) {
            const size_t rowoff = (size_t)(m0 + rbase + r) * N;
            float s = 0.f;
            #pragma unroll
            for (int g = 0; g < 4; ++g) {
                float x = acc[f][g][r];
                if constexpr (HAS_SCALE) x *= lred[rbase + r];
                if constexpr (ACC_SSQ) s += x * x;
                const int col = n0 + g * 64 + wn * 16 + cn;
                if constexpr (sizeof(CT) == 2) {
                    ((u16*)C)[rowoff + col] = f2bf(x);   // P: keep cached (gemm2 reads it)
                } else {
                    __builtin_nontemporal_store(x, &C[rowoff + col]);  // out: never re-read
                }
            }
            if constexpr (ACC_SSQ) {
                s += __shfl_xor(s, 1);
                s += __shfl_xor(s, 2);
                s += __shfl_xor(s, 4);
                s += __shfl_xor(s, 8);
                if (cn == 0) atomicAdd(&lred[rbase + r], s);  // 4 wn-waves/row
            }
        }
    }
    if constexpr (ACC_SSQ) {
        __syncthreads();
        if (tid < 256) atomicAdd(&ssq[m0 + tid], lred[tid]);  // 4 n-blocks/row
    }
}

// ---------- launch ----------
// B=4, S=8192, HID=PROJ=1024, NH=16, HD=64; M = B*S = 32768
// ws usage: 77.7 MiB (proven footprint). hbf lives in d_out's first half
// (dead after gemm1; gemm2 overwrites all of d_out — stream-ordered, safe).
extern "C" void kernel_launch(void* const* d_in, const int* in_sizes, int n_in,
                              void* d_out, int out_size, void* d_ws, size_t ws_size,
                              hipStream_t stream) {
    const float* h  = (const float*)d_in[0];   // [4,8192,1024]
    const float* Wq = (const float*)d_in[1];   // [1024,1024]
    const float* Wo = (const float*)d_in[7];   // [1024,1024]
    const float* M0 = (const float*)d_in[8];   // [4,16,64,64]
    float* out = (float*)d_out;

    char* ws = (char*)d_ws;
    u16*   hbf  = (u16*)d_out;                 // 67,108,864 B (first half of out)
    u16*   P    = (u16*)(ws);                  // 67,108,864 B
    u16*   WqT  = (u16*)(ws + 67108864);       //  2,097,152 B
    u16*   W2T  = (u16*)(ws + 69206016);       //  8,388,608 B
    float* ssq  = (float*)(ws + 77594624);     //    131,072 B  (end: 77,725,696)

    const int M = 32768, N = 1024, K = 1024;

    // one fused prep dispatch: w2t(256) | transpose(256) | ssq-zero(32) | cvt(16384)
    prep<<<16928, 256, 0, stream>>>(h, hbf, Wq, WqT, M0, Wo, W2T, ssq);
    // P = h @ Wq (bf16, un-normalized) + per-row ssq via atomics
    gemm256_8ph<1, 0, u16><<<512, 512, 0, stream>>>(
        hbf, WqT, P, ssq, M, N, K, 0, 0);
    // out = (1/max(sqrt(ssq),1e-12))[m] * (P @ W2T[batch]) ; batch = m >> 13
    gemm256_8ph<0, 1, float><<<512, 512, 0, stream>>>(
        P, W2T, out, ssq, M, N, K, (long long)1024 * 1024, 13);
}

// Round 9
// 375.441 us; speedup vs baseline: 1.6200x; 1.0115x over previous
//
#include <hip/hip_runtime.h>

typedef unsigned short u16;
typedef __bf16 bf16x8 __attribute__((ext_vector_type(8)));
typedef float   f32x4 __attribute__((ext_vector_type(4)));
typedef unsigned short u16x8 __attribute__((ext_vector_type(8)));

// ---------- helpers ----------
__device__ __forceinline__ u16 f2bf(float f) {
    unsigned int u = __builtin_bit_cast(unsigned int, f);
    u = u + 0x7FFFu + ((u >> 16) & 1u);   // round-to-nearest-even
    return (u16)(u >> 16);
}
__device__ __forceinline__ void gload16(const void* g, void* l) {
    __builtin_amdgcn_global_load_lds(
        (__attribute__((address_space(1))) void*)g,
        (__attribute__((address_space(3))) void*)l,
        16, 0, 0);
}

#define S_BARRIER() asm volatile("s_barrier" ::: "memory")

// ---------- fused prep: w2t | transpose | ssq-zero | cvt in ONE dispatch ----
// Blocks [0,256) build W2T, [256,512) transpose Wq, [512,544) zero ssq,
// [544,16928) cast h->bf16. Small jobs at low indices hide under the cvt
// stream. 3 blocks/CU (50 KiB LDS union) keeps cvt at HBM BW.
// NT policy (round-8 verified): h and Wq are single-use streams ->
// nontemporal LOADS, so the hbf/WqT outputs (gemm1's inputs) stay
// L3-resident (round-7 showed gemm1 re-fetching 50 MB of hbf when h's
// streaming reads evicted it; round-8 confirmed the fix).
// NT STORES are NOT used anywhere: round-8 measured gemm2's nt out-stores
// bypassing L2 write-combining -> WRITE_SIZE 135->173 MB, +11 us. Reverted.
__global__ __launch_bounds__(256) void prep(const float* __restrict__ h,
                                            u16* __restrict__ hbf,
                                            const float* __restrict__ Wq,
                                            u16* __restrict__ WqT,
                                            const float* __restrict__ M0,
                                            const float* __restrict__ Wo,
                                            u16* __restrict__ W2T,
                                            float* __restrict__ ssq) {
    __shared__ __align__(16) char smem[50176];
    const int bid = blockIdx.x;
    const int tid = threadIdx.x;

    if (bid < 256) {
        // ---- build_w2t: W2T[b][j][h*64+d] = sum_e M0[b,h,d,e]*Wo[h*64+e][j]
        // (results staged in padded LDS, written with lane=d -> 128 B-contig)
        float* m0s = (float*)smem;
        u16 (*outs)[66] = (u16 (*)[66])(smem + 16384);
        const int jq = bid & 3, hh = (bid >> 2) & 15, b = bid >> 6;
        const int j = jq * 256 + tid;
        const float* m0p = M0 + ((size_t)b * 16 + hh) * 4096;
        for (int i = tid; i < 4096; i += 256) m0s[i] = m0p[i];
        __syncthreads();
        float wo[64];
        #pragma unroll
        for (int e = 0; e < 64; ++e) wo[e] = Wo[(size_t)(hh * 64 + e) * 1024 + j];
        #pragma unroll 1
        for (int d = 0; d < 64; ++d) {
            float s = 0.f;
            #pragma unroll
            for (int e = 0; e < 64; ++e) s += m0s[d * 64 + e] * wo[e];
            outs[tid][d] = f2bf(s);
        }
        __syncthreads();
        const int d = tid & 63, jr = tid >> 6;
        u16* wp = W2T + (size_t)b * 1024 * 1024 + (size_t)(jq * 256) * 1024 + hh * 64 + d;
        #pragma unroll 1
        for (int it = 0; it < 64; ++it) {
            int jl = it * 4 + jr;
            wp[(size_t)jl * 1024] = outs[jl][d];
        }
    } else if (bid < 512) {
        // ---- transpose_cvt: Wq [K][N] fp32 -> WqT [N][K] bf16 (nt loads) ----
        u16 (*tile)[65] = (u16 (*)[65])smem;
        const int bb = bid - 256;
        const int c0 = (bb & 15) * 64;
        const int r0 = (bb >> 4) * 64;
        const int col = tid & 63;
        const int rb  = (tid >> 6) * 16;
        #pragma unroll
        for (int rr = 0; rr < 16; ++rr)
            tile[rb + rr][col] = f2bf(__builtin_nontemporal_load(
                &Wq[(size_t)(r0 + rb + rr) * 1024 + c0 + col]));
        __syncthreads();
        const int k = tid & 63;
        #pragma unroll
        for (int rr = 0; rr < 16; ++rr) {
            int n = c0 + rb + rr;
            WqT[(size_t)n * 1024 + r0 + k] = tile[k][rb + rr];
        }
    } else if (bid < 544) {
        // ---- ssq zero: 32768 floats across 32 blocks ----
        ((f32x4*)ssq)[(size_t)(bid - 512) * 256 + tid] = f32x4{0.f, 0.f, 0.f, 0.f};
    } else {
        // ---- cvt_bf16: h fp32 -> bf16, 8 elems/thread (nt loads on h) ----
        const int i = (bid - 544) * 256 + tid;
        if (i >= 4194304) return;
        const f32x4* xp = (const f32x4*)h + (size_t)i * 2;
        f32x4 a = __builtin_nontemporal_load(xp);
        f32x4 c = __builtin_nontemporal_load(xp + 1);
        u16x8 o;
        o[0]=f2bf(a[0]); o[1]=f2bf(a[1]); o[2]=f2bf(a[2]); o[3]=f2bf(a[3]);
        o[4]=f2bf(c[0]); o[5]=f2bf(c[1]); o[6]=f2bf(c[2]); o[7]=f2bf(c[3]);
        ((u16x8*)hbf)[i] = o;
    }
}

// ---------- GEMM: 256x256 tile, BK=64, 8-phase (T2+T3+T4+T5) ----------
// C[M,N] = A[M,K] * Bt[N,K]^T, bf16 in, fp32 acc.  (round-3/4 verified body,
// 886 TF @ K=1024 = plain-HIP 8-phase template ceiling for this shape.)
// 4 barriers/K-tile; counted vmcnt(6) per tile; tail tiles drain vmcnt(0).
// Stage schedule per tile T: p0:(T+1).A1  p1:(T+2).A0  p2:(T+2).B0
// p3:(T+2).B1 + vmcnt(6) (retires all of tile T+1; 6 = 3 half-tiles left).
// LDS swizzle (both-sides, rule #21): linear dest for global_load_lds, global
// SOURCE chunk pre-permuted chunk^=row&7, reads XOR byte^=((row&7)<<4).
// Grid 512 = 128 m-tiles x 4 n-tiles; xcd=id&7, all 4 n-tiles of an m-tile
// on one XCD (A panel L2-resident; 512%8==0 bijective).
// C-writes are ordinary cached stores: L2 write-combining aggregates the
// per-lane 4 B stores into full lines (round-8: nt stores cost +38 MB/+11 us).

#define STAGE(GB, SLOT) \
    gload16((GB) + g0, (char*)(SLOT) + d0); \
    gload16((GB) + g1, (char*)(SLOT) + d1);

#define READ_A(SLOT) \
    _Pragma("unroll") for (int f = 0; f < 4; ++f) \
    _Pragma("unroll") for (int kk = 0; kk < 2; ++kk) \
        a[f][kk] = *(const bf16x8*)((const char*)(SLOT) + \
            (((rhA + f * 32) << 7) + (cA ^ (kk << 6))));

#define READ_B(SLOT, GB) \
    _Pragma("unroll") for (int g = 0; g < 2; ++g) \
    _Pragma("unroll") for (int kk = 0; kk < 2; ++kk) \
        b[(GB) + g][kk] = *(const bf16x8*)((const char*)(SLOT) + \
            (((rhB + g * 64) << 7) + (cB ^ (kk << 6))));

#define MFMA_QUAD(FB, GB) \
    __builtin_amdgcn_s_setprio(1); \
    _Pragma("unroll") for (int f = 0; f < 4; ++f) \
    _Pragma("unroll") for (int g = 0; g < 2; ++g) \
    _Pragma("unroll") for (int kk = 0; kk < 2; ++kk) \
        acc[(FB) + f][(GB) + g] = __builtin_amdgcn_mfma_f32_16x16x32_bf16( \
            a[f][kk], b[(GB) + g][kk], acc[(FB) + f][(GB) + g], 0, 0, 0); \
    __builtin_amdgcn_s_setprio(0);

#define TILE_BODY(T, BB, VMW) { \
    bf16x8 a[4][2], b[4][2]; \
    /* p0: reads a0,b01(T); stage (T+1).A1 (slot's old a1(T-1) read done   */ \
    /* before T-1.p2's barrier).                                           */ \
    READ_A(lds[BB][0]); \
    READ_B(lds[BB][2], 0); \
    if ((T) + 1 < NT) { STAGE(A1p + ((T) + 1) * 64, lds[(BB) ^ 1][1]); } \
    MFMA_QUAD(0, 0); \
    S_BARRIER(); \
    /* p1: reads b23(T); stage (T+2).A0 over a0(T) (reads done < p0 bar). */ \
    READ_B(lds[BB][3], 2); \
    if ((T) + 2 < NT) { STAGE(A0p + ((T) + 2) * 64, lds[BB][0]); } \
    MFMA_QUAD(0, 2); \
    S_BARRIER(); \
    /* p2: reads a1(T); stage (T+2).B0 over b01(T) (reads done < p0 bar). */ \
    READ_A(lds[BB][1]); \
    if ((T) + 2 < NT) { STAGE(B0p + ((T) + 2) * 64, lds[BB][2]); } \
    MFMA_QUAD(4, 0); \
    S_BARRIER(); \
    /* p3: stage (T+2).B1 over b23(T) (reads done < p1 bar); counted vmcnt */ \
    /* publishes tile T+1 for next p0.                                     */ \
    if ((T) + 2 < NT) { STAGE(B1p + ((T) + 2) * 64, lds[BB][3]); } \
    MFMA_QUAD(4, 2); \
    asm volatile(VMW ::: "memory"); \
    S_BARRIER(); \
}

template <int ACC_SSQ, int HAS_SCALE, typename CT>
__global__ __launch_bounds__(512) void gemm256_8ph(const u16* __restrict__ A,
                                                   const u16* __restrict__ Bt,
                                                   CT* __restrict__ C,
                                                   float* __restrict__ ssq,
                                                   int M, int N, int K,
                                                   long long bt_batch_stride,
                                                   int rpb_log2) {
    __shared__ u16 lds[2][4][8192];   // 128 KiB
    const int tid  = threadIdx.x;
    const int lane = tid & 63;
    const int w    = tid >> 6;
    const int wm   = w >> 2;          // 0..1
    const int wn   = w & 3;           // 0..3

    // XCD-aware swizzle: 4 n-tiles of an m-tile share one XCD's L2.
    const int id  = blockIdx.x;
    const int xcd = id & 7;
    const int loc = id >> 3;
    const int mpx = (M >> 8) >> 3;            // m-tiles per XCD (16)
    const int mt  = xcd * mpx + (loc >> 2);
    const int ntt = loc & 3;
    const int m0  = mt << 8;
    const int n0  = ntt << 8;

    const u16* Btb = Bt + (size_t)(m0 >> rpb_log2) * (size_t)bt_batch_stride;
    const u16* A0p = A   + (size_t)m0 * K;
    const u16* A1p = A0p + (size_t)128 * K;
    const u16* B0p = Btb + (size_t)n0 * K;
    const u16* B1p = B0p + (size_t)128 * K;

    // staging: thread t loads rows (t>>3) and 64+(t>>3); source chunk
    // pre-swizzled so linear LDS + swizzled read is consistent (involution).
    const int    trow   = tid >> 3;
    const int    tchunk = (tid & 7) ^ (trow & 7);
    const size_t g0 = (size_t)trow * K + (size_t)tchunk * 8;   // u16 elems
    const size_t g1 = g0 + (size_t)64 * K;
    const int    d0 = tid * 16;                                 // bytes
    const int    d1 = d0 + 8192;

    const int NT = K >> 6;    // K-tiles (16); NT even, NT >= 4 assumed

    // per-lane LDS read bases (swizzle XOR constant per lane)
    const int rm  = lane & 15;
    const int kqb = (lane >> 4) << 4;                // byte offset of kq
    const int rhA = wm * 16 + rm;
    const int cA  = kqb ^ ((rhA & 7) << 4);
    const int rhB = wn * 16 + rm;
    const int cB  = kqb ^ ((rhB & 7) << 4);

    f32x4 acc[8][4] = {};

    // ---- prologue: stage T0 fully + T1.{A0,B0,B1}; vmcnt(6) -> T0 landed ----
    STAGE(A0p + 0,  lds[0][0]);
    STAGE(B0p + 0,  lds[0][2]);
    STAGE(B1p + 0,  lds[0][3]);
    STAGE(A1p + 0,  lds[0][1]);
    STAGE(A0p + 64, lds[1][0]);
    STAGE(B0p + 64, lds[1][2]);
    STAGE(B1p + 64, lds[1][3]);
    asm volatile("s_waitcnt vmcnt(6)" ::: "memory");
    S_BARRIER();

    #pragma unroll 1
    for (int T = 0; T < NT - 2; T += 2) {
        TILE_BODY(T, 0, "s_waitcnt vmcnt(6)");
        TILE_BODY(T + 1, 1, "s_waitcnt vmcnt(6)");
    }
    // tail: vmcnt(6) at NT-2.p3 would only prove A0(NT-1) landed; drain fully.
    TILE_BODY(NT - 2, 0, "s_waitcnt vmcnt(0)");
    TILE_BODY(NT - 1, 1, "s_waitcnt vmcnt(0)");

    // ---- epilogue ----  C/D: col=lane&15, row=(lane>>4)*4+reg [m89]
    __syncthreads();
    float* lred = (float*)&lds[0][0][0];   // 256 floats, LDS reuse
    if constexpr (HAS_SCALE) {
        if (tid < 256) {
            float q = ssq[m0 + tid];
            lred[tid] = 1.0f / fmaxf(sqrtf(q), 1e-12f);
        }
        __syncthreads();
    }
    if constexpr (ACC_SSQ) {
        if (tid < 256) lred[tid] = 0.f;
        __syncthreads();
    }
    const int cn = lane & 15;
    const int rq = (lane >> 4) * 4;
    #pragma unroll
    for (int f = 0; f < 8; ++f) {
        const int rbase = f * 32 + wm * 16 + rq;
        #pragma unroll
        for (int r = 0; r < 4; ++r) {
            const size_t rowoff = (size_t)(m0 + rbase + r) * N;
            float s = 0.f;
            #pragma unroll
            for (int g = 0; g < 4; ++g) {
                float x = acc[f][g][r];
                if constexpr (HAS_SCALE) x *= lred[rbase + r];
                if constexpr (ACC_SSQ) s += x * x;
                const int col = n0 + g * 64 + wn * 16 + cn;
                if constexpr (sizeof(CT) == 2) ((u16*)C)[rowoff + col] = f2bf(x);
                else                           C[rowoff + col] = x;
            }
            if constexpr (ACC_SSQ) {
                s += __shfl_xor(s, 1);
                s += __shfl_xor(s, 2);
                s += __shfl_xor(s, 4);
                s += __shfl_xor(s, 8);
                if (cn == 0) atomicAdd(&lred[rbase + r], s);  // 4 wn-waves/row
            }
        }
    }
    if constexpr (ACC_SSQ) {
        __syncthreads();
        if (tid < 256) atomicAdd(&ssq[m0 + tid], lred[tid]);  // 4 n-blocks/row
    }
}

// ---------- launch ----------
// B=4, S=8192, HID=PROJ=1024, NH=16, HD=64; M = B*S = 32768
// ws usage: 77.7 MiB (proven footprint). hbf lives in d_out's first half
// (dead after gemm1; gemm2 overwrites all of d_out — stream-ordered, safe).
extern "C" void kernel_launch(void* const* d_in, const int* in_sizes, int n_in,
                              void* d_out, int out_size, void* d_ws, size_t ws_size,
                              hipStream_t stream) {
    const float* h  = (const float*)d_in[0];   // [4,8192,1024]
    const float* Wq = (const float*)d_in[1];   // [1024,1024]
    const float* Wo = (const float*)d_in[7];   // [1024,1024]
    const float* M0 = (const float*)d_in[8];   // [4,16,64,64]
    float* out = (float*)d_out;

    char* ws = (char*)d_ws;
    u16*   hbf  = (u16*)d_out;                 // 67,108,864 B (first half of out)
    u16*   P    = (u16*)(ws);                  // 67,108,864 B
    u16*   WqT  = (u16*)(ws + 67108864);       //  2,097,152 B
    u16*   W2T  = (u16*)(ws + 69206016);       //  8,388,608 B
    float* ssq  = (float*)(ws + 77594624);     //    131,072 B  (end: 77,725,696)

    const int M = 32768, N = 1024, K = 1024;

    // one fused prep dispatch: w2t(256) | transpose(256) | ssq-zero(32) | cvt(16384)
    prep<<<16928, 256, 0, stream>>>(h, hbf, Wq, WqT, M0, Wo, W2T, ssq);
    // P = h @ Wq (bf16, un-normalized) + per-row ssq via atomics
    gemm256_8ph<1, 0, u16><<<512, 512, 0, stream>>>(
        hbf, WqT, P, ssq, M, N, K, 0, 0);
    // out = (1/max(sqrt(ssq),1e-12))[m] * (P @ W2T[batch]) ; batch = m >> 13
    gemm256_8ph<0, 1, float><<<512, 512, 0, stream>>>(
        P, W2T, out, ssq, M, N, K, (long long)1024 * 1024, 13);
}